// Round 10
// baseline (113.688 us; speedup 1.0000x reference)
//
#include <hip/hip_runtime.h>

// MHA: B=4, T=1024, D=1024, H=16, HD=64. Causal mask, interleaved RoPE.
// bf16 MFMA (16x16x32) everywhere, fp32 accumulate.
// R10: attn unpaired -> grid (64 bh x 16 qt) = 1024 single-q-tile blocks,
// 40KB LDS = 4 blocks/CU (launch_bounds(256,4)) so full-drain barriers of
// one block hide under the other 3 (m114 inter-block overlap). oproj gets
// launch_bounds(256,3). qkv = R4/R9 proven 2-phase (49-50us).

#define T_SEQ 1024
#define NH    16
#define HDIM  64
#define DM    1024
#define MTOK  4096   // B*T

typedef __attribute__((ext_vector_type(8))) short short8;
typedef __attribute__((ext_vector_type(4))) float f32x4;
typedef unsigned short u16;

__device__ __forceinline__ u16 f2bf(float f) {
  unsigned int u = __builtin_bit_cast(unsigned int, f);
  u += 0x7fffu + ((u >> 16) & 1u);
  return (u16)(u >> 16);
}

// async global->LDS, 16B per lane. LDS dest must be wave-uniform base + lane*16.
__device__ __forceinline__ void gll16(const void* g, void* l) {
  __builtin_amdgcn_global_load_lds(
      (const __attribute__((address_space(1))) unsigned int*)(unsigned long long)(g),
      (__attribute__((address_space(3))) unsigned int*)(unsigned int)(unsigned long long)(l),
      16, 0, 0);
}

// ---------------- prep: x->bf16, W->bf16 (fused qkv+o), rope tables ----------------
__global__ void prep_kernel(const float* __restrict__ x,
                            const float* __restrict__ Wq, const float* __restrict__ Wk,
                            const float* __restrict__ Wv, const float* __restrict__ Wo,
                            u16* __restrict__ xb, u16* __restrict__ wall,
                            float* __restrict__ ctab, float* __restrict__ stab) {
  const int bid = blockIdx.x, tid = threadIdx.x;
  if (bid < 8192) {
    const float* src;
    u16* dst;
    int i;
    if (bid < 4096) {
      src = x; dst = xb; i = bid * 256 + tid;
    } else {
      const int w = (bid - 4096) >> 10;
      src = w == 0 ? Wq : w == 1 ? Wk : w == 2 ? Wv : Wo;
      dst = wall + (size_t)w * (DM * DM);
      i = ((bid - 4096) & 1023) * 256 + tid;
    }
    float4 f = ((const float4*)src)[i];
    unsigned long long pk = (unsigned long long)f2bf(f.x)
                          | ((unsigned long long)f2bf(f.y) << 16)
                          | ((unsigned long long)f2bf(f.z) << 32)
                          | ((unsigned long long)f2bf(f.w) << 48);
    ((unsigned long long*)dst)[i] = pk;
  } else {
    const int idx = (bid - 8192) * 256 + tid;  // T*32
    const int t = idx >> 5, i = idx & 31;
    float inv = powf(10000.f, -(float)i * (1.0f / 32.0f));
    float f = (float)t * inv;
    ctab[idx] = cosf(f);
    stab[idx] = sinf(f);
  }
}

// ---------------- single-barrier pipelined GEMM mainloop (R4, proven) ----------------
template<int BM, int BN, int AI, int BI, int MI, int NJ>
__device__ __forceinline__ void gemm_pipe2(
    const u16* __restrict__ A, const u16* __restrict__ Bw,
    int m0, int n0, u16* As, u16* Bs, f32x4 acc[MI][NJ]) {
  const int tid = threadIdx.x, lane = tid & 63, wave = tid >> 6;
  const int wr = wave >> 1, wc = wave & 1;
  const int srcswz = ((lane & 7) ^ (lane >> 3)) * 8;  // u16 offset within K-slice
  const int NT = DM / 64;

#define STAGE2(t, b)                                                         \
  do {                                                                       \
    _Pragma("unroll") for (int i = 0; i < AI; ++i) {                         \
      const int q = (wave * AI + i) * 64 + lane;                             \
      gll16(&A[(size_t)(m0 + (q >> 3)) * DM + (t) * 64 + srcswz],            \
            &As[(b) * BM * 64 + q * 8]);                                     \
    }                                                                        \
    _Pragma("unroll") for (int i = 0; i < BI; ++i) {                         \
      const int q = (wave * BI + i) * 64 + lane;                             \
      gll16(&Bw[(size_t)(n0 + (q >> 3)) * DM + (t) * 64 + srcswz],           \
            &Bs[(b) * BN * 64 + q * 8]);                                     \
    }                                                                        \
  } while (0)

  STAGE2(0, 0);
  __syncthreads();
  int buf = 0;
  const int arow0 = wr * (BM / 2) + (lane & 15);
  const int brow0 = wc * (BN / 2) + (lane & 15);
  const int c0 = (((lane >> 4)) ^ (lane & 7)) * 8;      // kk=0 chunk (XOR row&7 = lane&7)
  const int c1 = ((4 + (lane >> 4)) ^ (lane & 7)) * 8;  // kk=1 chunk
  for (int t = 0; t < NT; ++t) {
    if (t + 1 < NT) STAGE2(t + 1, buf ^ 1);
    short8 af[MI][2], bf[NJ][2];
#pragma unroll
    for (int i = 0; i < MI; ++i) {
      const int r = buf * BM * 64 + (arow0 + i * 16) * 64;
      af[i][0] = *(const short8*)&As[r + c0];
      af[i][1] = *(const short8*)&As[r + c1];
    }
#pragma unroll
    for (int j = 0; j < NJ; ++j) {
      const int r = buf * BN * 64 + (brow0 + j * 16) * 64;
      bf[j][0] = *(const short8*)&Bs[r + c0];
      bf[j][1] = *(const short8*)&Bs[r + c1];
    }
#pragma unroll
    for (int i = 0; i < MI; ++i)
#pragma unroll
      for (int j = 0; j < NJ; ++j) {
        acc[i][j] = __builtin_amdgcn_mfma_f32_16x16x32_bf16(af[i][0], bf[j][0], acc[i][j], 0, 0, 0);
        acc[i][j] = __builtin_amdgcn_mfma_f32_16x16x32_bf16(af[i][1], bf[j][1], acc[i][j], 0, 0, 0);
      }
    __syncthreads();
    buf ^= 1;
  }
#undef STAGE2
}

// ---------------- fused QKV projection + bias + RoPE + layout ----------------
// Tile 128x192, grid 512 1-D, n-major (R9, proven).
__global__ __launch_bounds__(256, 2) void qkv_kernel(
    const u16* __restrict__ xb, const u16* __restrict__ wqkv,
    const float* __restrict__ bq, const float* __restrict__ bk, const float* __restrict__ bv,
    const float* __restrict__ ctab, const float* __restrict__ stab,
    u16* __restrict__ qbuf, u16* __restrict__ kbuf, u16* __restrict__ vt) {
  __shared__ __align__(16) u16 As[2 * 128 * 64];   // 32 KB
  __shared__ __align__(16) u16 Bs[2 * 192 * 64];   // 48 KB
  const int lin = blockIdx.x;                      // 512 = 16 n-groups * 32 m
  const int m0 = (lin & 31) * 128;
  const int n0 = (lin >> 5) * 192;                 // fused col across Wq|Wk|Wv
  f32x4 acc[4][6];
#pragma unroll
  for (int i = 0; i < 4; ++i)
#pragma unroll
    for (int j = 0; j < 6; ++j)
#pragma unroll
      for (int r = 0; r < 4; ++r) acc[i][j][r] = 0.f;
  gemm_pipe2<128, 192, 4, 6, 4, 6>(xb, wqkv, m0, n0, As, Bs, acc);

  const int lane = threadIdx.x & 63, wave = threadIdx.x >> 6;
  const int wr = wave >> 1, wc = wave & 1;
#pragma unroll
  for (int i = 0; i < 4; ++i) {
#pragma unroll
    for (int j = 0; j < 6; ++j) {
      const int e = n0 + wc * 96 + j * 16 + (lane & 15);   // global fused col
      const int mode = e >> 10;                             // 0=q 1=k 2=v (uniform per j-block)
      const float* bias = mode == 0 ? bq : (mode == 1 ? bk : bv);
      const float bval = bias[e & 1023];
      const int h = (e >> 6) & 15, hd = e & 63;
#pragma unroll
      for (int r = 0; r < 4; ++r) {
        const int m = m0 + wr * 64 + i * 16 + ((lane >> 4) * 4) + r;
        const int b = m >> 10, t = m & 1023;
        float v = acc[i][j][r] + bval;
        if (mode < 2) {
          float p = __shfl_xor(v, 1);  // partner within the (even,odd) pair
          const int fi = hd >> 1;
          const float cc = ctab[t * 32 + fi], ss = stab[t * 32 + fi];
          v = (hd & 1) ? (v * cc + p * ss) : (v * cc - p * ss);
          u16* dst = mode == 0 ? qbuf : kbuf;
          dst[(((size_t)(b * NH + h) * T_SEQ + t) << 6) + hd] = f2bf(v);
        } else {
          vt[(((size_t)(b * NH + h) * HDIM + hd) << 10) + t] = f2bf(v);
        }
      }
    }
  }
}

// ---------------- flash attention ----------------
// R10: unpaired. Block = (b,h,qt): one 64-row q-tile, nkv = qt+1 KV tiles.
// Grid (64, 16) = 1024 blocks; 40KB LDS -> 4 blocks/CU for inter-block
// overlap of the full-drain barriers. dbuf + swizzle + MFMA l-sum (R9).
__global__ __launch_bounds__(256, 4) void attn_kernel(
    const u16* __restrict__ qbuf, const u16* __restrict__ kbuf,
    const u16* __restrict__ vtb, u16* __restrict__ ctx) {
  __shared__ __align__(16) u16 Ks[2][64 * 64];   // [kv][hd] swizzled
  __shared__ __align__(16) u16 Vs[2][64 * 64];   // [hd][kv] swizzled (V^T tile)
  __shared__ __align__(16) u16 Psm[4][16 * 64];  // per-wave P, swizzled
  const int bh = blockIdx.x;
  const int b = bh >> 4, h = bh & 15;
  const int tid = threadIdx.x, lane = tid & 63, wave = tid >> 6;
  const u16* Qp = qbuf + (size_t)bh * T_SEQ * HDIM;
  const u16* Kp = kbuf + (size_t)bh * T_SEQ * HDIM;
  const u16* Vp = vtb + (size_t)bh * HDIM * T_SEQ;
  u16* Pw = &Psm[wave][0];
  const float SC = 0.18033688f;                  // 0.125 * log2(e)

  const int srow = tid >> 3;                     // staging row (0..31, +32 for c=1)
  const int schx = ((tid & 7) ^ (srow & 7)) * 8; // pre-swizzled chunk (u16 offset)
  const int lx = lane & 7;                       // row&7 for all read rows below

  short8 onesf;
#pragma unroll
  for (int i = 0; i < 8; ++i) onesf[i] = (short)0x3F80;  // bf16 1.0

#define STG(kvt, bb)                                                            \
  do {                                                                          \
    _Pragma("unroll") for (int c = 0; c < 2; ++c) {                             \
      const int rr = c * 32 + srow;                                             \
      gll16(&Kp[(kvt) * 4096 + rr * 64 + schx], &Ks[bb][c * 2048 + tid * 8]);   \
      gll16(&Vp[(size_t)rr * T_SEQ + (kvt) * 64 + schx], &Vs[bb][c * 2048 + tid * 8]); \
    }                                                                           \
  } while (0)

  const int qt = blockIdx.y;
  const int q0 = qt * 64;
  const int nkv = qt + 1;
  const int qrow = q0 + wave * 16 + (lane & 15);
  const short8 qf0 = *(const short8*)&Qp[qrow * 64 + ((lane >> 4) * 8)];
  const short8 qf1 = *(const short8*)&Qp[qrow * 64 + 32 + ((lane >> 4) * 8)];

  f32x4 acc_o[4], accl;
  float m_r[4];
#pragma unroll
  for (int i = 0; i < 4; ++i) {
#pragma unroll
    for (int r = 0; r < 4; ++r) acc_o[i][r] = 0.f;
    accl[i] = 0.f;
    m_r[i] = -__builtin_inff();
  }

  STG(0, 0);
  int cur = 0;

  for (int kvt = 0; kvt < nkv; ++kvt) {
    __syncthreads();                       // buf[cur] staged (vmcnt drained)
    if (kvt + 1 < nkv) STG(kvt + 1, cur ^ 1);

    // S = Q K^T (16x64 per wave), scaled into exp2 domain
    f32x4 sacc[4];
#pragma unroll
    for (int cb = 0; cb < 4; ++cb) {
#pragma unroll
      for (int r = 0; r < 4; ++r) sacc[cb][r] = 0.f;
      const int krow = cb * 16 + (lane & 15);
      const short8 kf0 = *(const short8*)&Ks[cur][krow * 64 + (((lane >> 4) ^ lx) * 8)];
      const short8 kf1 = *(const short8*)&Ks[cur][krow * 64 + (((4 + (lane >> 4)) ^ lx) * 8)];
      sacc[cb] = __builtin_amdgcn_mfma_f32_16x16x32_bf16(qf0, kf0, sacc[cb], 0, 0, 0);
      sacc[cb] = __builtin_amdgcn_mfma_f32_16x16x32_bf16(qf1, kf1, sacc[cb], 0, 0, 0);
    }
    if (kvt == qt) {
      // diagonal tile: scale + causal mask
      const int trow_base = q0 + wave * 16 + ((lane >> 4) * 4);
#pragma unroll
      for (int cb = 0; cb < 4; ++cb) {
        const int scol = kvt * 64 + cb * 16 + (lane & 15);
#pragma unroll
        for (int r = 0; r < 4; ++r)
          sacc[cb][r] = (scol > trow_base + r) ? -__builtin_inff() : sacc[cb][r] * SC;
      }
    } else {
#pragma unroll
      for (int cb = 0; cb < 4; ++cb)
#pragma unroll
        for (int r = 0; r < 4; ++r) sacc[cb][r] *= SC;
    }
    // online softmax: row-max via 4-round shuffle; row-sum via MFMA below
    float mt[4];
#pragma unroll
    for (int r = 0; r < 4; ++r)
      mt[r] = fmaxf(fmaxf(sacc[0][r], sacc[1][r]), fmaxf(sacc[2][r], sacc[3][r]));
#pragma unroll
    for (int off = 1; off < 16; off <<= 1)
#pragma unroll
      for (int r = 0; r < 4; ++r) mt[r] = fmaxf(mt[r], __shfl_xor(mt[r], off));
    float sf[4];
#pragma unroll
    for (int r = 0; r < 4; ++r) {
      const float mn = fmaxf(m_r[r], mt[r]);
      sf[r] = exp2f(m_r[r] - mn);
      m_r[r] = mn;
    }
#pragma unroll
    for (int cb = 0; cb < 4; ++cb)
#pragma unroll
      for (int r = 0; r < 4; ++r) sacc[cb][r] = exp2f(sacc[cb][r] - m_r[r]);
#pragma unroll
    for (int r = 0; r < 4; ++r) accl[r] *= sf[r];
#pragma unroll
    for (int hb = 0; hb < 4; ++hb)
#pragma unroll
      for (int r = 0; r < 4; ++r) acc_o[hb][r] *= sf[r];

    // P (C-layout) -> LDS (swizzled) -> A-layout
#pragma unroll
    for (int cb = 0; cb < 4; ++cb)
#pragma unroll
      for (int r = 0; r < 4; ++r) {
        const int prow = (lane >> 4) * 4 + r;
        Pw[prow * 64 + ((cb * 16 + (lane & 15)) ^ ((prow & 7) << 3))] = f2bf(sacc[cb][r]);
      }

    // O += P V; l += P * ones
    const int prr = lane & 15;
#pragma unroll
    for (int kc = 0; kc < 2; ++kc) {
      const short8 pf = *(const short8*)&Pw[prr * 64 + (((kc * 4 + (lane >> 4)) ^ lx) * 8)];
      accl = __builtin_amdgcn_mfma_f32_16x16x32_bf16(pf, onesf, accl, 0, 0, 0);
#pragma unroll
      for (int hb = 0; hb < 4; ++hb) {
        const int vrow = hb * 16 + (lane & 15);
        const short8 vf = *(const short8*)&Vs[cur][vrow * 64 + (((kc * 4 + (lane >> 4)) ^ lx) * 8)];
        acc_o[hb] = __builtin_amdgcn_mfma_f32_16x16x32_bf16(pf, vf, acc_o[hb], 0, 0, 0);
      }
    }
    cur ^= 1;
  }

  // epilogue: ctx[b][t][h][hd] bf16
#pragma unroll
  for (int hb = 0; hb < 4; ++hb) {
    const int hd = hb * 16 + (lane & 15);
#pragma unroll
    for (int r = 0; r < 4; ++r) {
      const int t = q0 + wave * 16 + ((lane >> 4) * 4) + r;
      const float v = acc_o[hb][r] / accl[r];
      ctx[((size_t)(b * T_SEQ + t) * NH + h) * HDIM + hd] = f2bf(v);
    }
  }
#undef STG
}

// ---------------- output projection -> fp32 d_out ----------------
// Tile 64x128, grid 512 1-D, n-major. 48KB LDS -> allow 3 resident blocks.
__global__ __launch_bounds__(256, 3) void oproj_kernel(
    const u16* __restrict__ ctx, const u16* __restrict__ Wob,
    const float* __restrict__ bo, float* __restrict__ out) {
  __shared__ __align__(16) u16 As[2 * 64 * 64];    // 16 KB
  __shared__ __align__(16) u16 Bs[2 * 128 * 64];   // 32 KB
  const int lin = blockIdx.x;                      // 512 = 8 n-groups * 64 m
  const int m0 = (lin & 63) * 64;
  const int n0 = (lin >> 6) * 128;
  f32x4 acc[2][4];
#pragma unroll
  for (int i = 0; i < 2; ++i)
#pragma unroll
    for (int j = 0; j < 4; ++j)
#pragma unroll
      for (int r = 0; r < 4; ++r) acc[i][j][r] = 0.f;
  gemm_pipe2<64, 128, 2, 4, 2, 4>(ctx, Wob, m0, n0, As, Bs, acc);
  const int lane = threadIdx.x & 63, wave = threadIdx.x >> 6;
  const int wr = wave >> 1, wc = wave & 1;
#pragma unroll
  for (int i = 0; i < 2; ++i)
#pragma unroll
    for (int j = 0; j < 4; ++j) {
      const int e = n0 + wc * 64 + j * 16 + (lane & 15);
      const float bval = bo[e];
#pragma unroll
      for (int r = 0; r < 4; ++r) {
        const int m = m0 + wr * 32 + i * 16 + ((lane >> 4) * 4) + r;
        out[(size_t)m * DM + e] = acc[i][j][r] + bval;
      }
    }
}

extern "C" void kernel_launch(void* const* d_in, const int* in_sizes, int n_in,
                              void* d_out, int out_size, void* d_ws, size_t ws_size,
                              hipStream_t stream) {
  const float* x  = (const float*)d_in[0];
  const float* Wq = (const float*)d_in[1];
  const float* bq = (const float*)d_in[2];
  const float* Wk = (const float*)d_in[3];
  const float* bk = (const float*)d_in[4];
  const float* Wv = (const float*)d_in[5];
  const float* bv = (const float*)d_in[6];
  const float* Wo = (const float*)d_in[7];
  const float* bo = (const float*)d_in[8];

  char* w = (char*)d_ws;
  u16* xb   = (u16*)(w);
  u16* wall = (u16*)(w + (8ull << 20));   // Wq|Wk|Wv|Wo bf16, 2MB each
  u16* wob  = (u16*)(w + (14ull << 20));
  u16* qb   = (u16*)(w + (16ull << 20));
  u16* kb   = (u16*)(w + (24ull << 20));
  u16* vtb  = (u16*)(w + (32ull << 20));
  u16* ctxb = (u16*)(w + (40ull << 20));
  float* ctab = (float*)(w + (48ull << 20));
  float* stab = ctab + T_SEQ * 32;

  prep_kernel<<<dim3(8192 + 128), 256, 0, stream>>>(x, Wq, Wk, Wv, Wo, xb, wall, ctab, stab);
  qkv_kernel<<<dim3(512), 256, 0, stream>>>(
      xb, wall, bq, bk, bv, ctab, stab, qb, kb, vtb);
  attn_kernel<<<dim3(64, 16), 256, 0, stream>>>(qb, kb, vtb, ctxb);
  oproj_kernel<<<dim3(512), 256, 0, stream>>>(ctxb, wob, bo, (float*)d_out);
}

// Round 11
// 110.470 us; speedup vs baseline: 1.0291x; 1.0291x over previous
//
#include <hip/hip_runtime.h>

// MHA: B=4, T=1024, D=1024, H=16, HD=64. Causal mask, interleaved RoPE.
// bf16 MFMA (16x16x32) everywhere, fp32 accumulate.
// R11: qkv -> 256x192 tile, BK=64, 8 waves (4m x 2n), R4's proven
// single-barrier 2-phase schedule, 112KB static LDS, grid 256 (1/CU,
// n-major). 2 waves/SIMD double MFMA issue per barrier stall. attn/oproj
// reverted to R9 exact (110.6us config).

#define T_SEQ 1024
#define NH    16
#define HDIM  64
#define DM    1024
#define MTOK  4096   // B*T

typedef __attribute__((ext_vector_type(8))) short short8;
typedef __attribute__((ext_vector_type(4))) float f32x4;
typedef unsigned short u16;

__device__ __forceinline__ u16 f2bf(float f) {
  unsigned int u = __builtin_bit_cast(unsigned int, f);
  u += 0x7fffu + ((u >> 16) & 1u);
  return (u16)(u >> 16);
}

// async global->LDS, 16B per lane. LDS dest must be wave-uniform base + lane*16.
__device__ __forceinline__ void gll16(const void* g, void* l) {
  __builtin_amdgcn_global_load_lds(
      (const __attribute__((address_space(1))) unsigned int*)(unsigned long long)(g),
      (__attribute__((address_space(3))) unsigned int*)(unsigned int)(unsigned long long)(l),
      16, 0, 0);
}

// ---------------- prep: x->bf16, W->bf16 (fused qkv+o), rope tables ----------------
__global__ void prep_kernel(const float* __restrict__ x,
                            const float* __restrict__ Wq, const float* __restrict__ Wk,
                            const float* __restrict__ Wv, const float* __restrict__ Wo,
                            u16* __restrict__ xb, u16* __restrict__ wall,
                            float* __restrict__ ctab, float* __restrict__ stab) {
  const int bid = blockIdx.x, tid = threadIdx.x;
  if (bid < 8192) {
    const float* src;
    u16* dst;
    int i;
    if (bid < 4096) {
      src = x; dst = xb; i = bid * 256 + tid;
    } else {
      const int w = (bid - 4096) >> 10;
      src = w == 0 ? Wq : w == 1 ? Wk : w == 2 ? Wv : Wo;
      dst = wall + (size_t)w * (DM * DM);
      i = ((bid - 4096) & 1023) * 256 + tid;
    }
    float4 f = ((const float4*)src)[i];
    unsigned long long pk = (unsigned long long)f2bf(f.x)
                          | ((unsigned long long)f2bf(f.y) << 16)
                          | ((unsigned long long)f2bf(f.z) << 32)
                          | ((unsigned long long)f2bf(f.w) << 48);
    ((unsigned long long*)dst)[i] = pk;
  } else {
    const int idx = (bid - 8192) * 256 + tid;  // T*32
    const int t = idx >> 5, i = idx & 31;
    float inv = powf(10000.f, -(float)i * (1.0f / 32.0f));
    float f = (float)t * inv;
    ctab[idx] = cosf(f);
    stab[idx] = sinf(f);
  }
}

// ---------------- single-barrier pipelined GEMM mainloop (R4 schedule) ----------------
// A:[M][1024] bf16, Bw:[N][1024] bf16 (row = output col). BK=64, NT=16.
// MW x NW wave grid; per-wave output (BM/MW) x (BN/NW) = MI*16 x NJ*16.
// LDS: row-major [rows][64], 16B chunk c of row r stored at c ^ (r&7)
// (inverse-swizzle on GLOBAL source; reads same XOR). One barrier/iter.
template<int BM, int BN, int AI, int BI, int MI, int NJ, int MW, int NW>
__device__ __forceinline__ void gemm_pipe2(
    const u16* __restrict__ A, const u16* __restrict__ Bw,
    int m0, int n0, u16* As, u16* Bs, f32x4 acc[MI][NJ]) {
  const int tid = threadIdx.x, lane = tid & 63, wave = tid >> 6;
  const int wr = wave / NW, wc = wave % NW;
  const int srcswz = ((lane & 7) ^ (lane >> 3)) * 8;  // u16 offset within K-slice
  const int NT = DM / 64;

#define STAGE2(t, b)                                                         \
  do {                                                                       \
    _Pragma("unroll") for (int i = 0; i < AI; ++i) {                         \
      const int q = (wave * AI + i) * 64 + lane;                             \
      gll16(&A[(size_t)(m0 + (q >> 3)) * DM + (t) * 64 + srcswz],            \
            &As[(b) * BM * 64 + q * 8]);                                     \
    }                                                                        \
    _Pragma("unroll") for (int i = 0; i < BI; ++i) {                         \
      const int q = (wave * BI + i) * 64 + lane;                             \
      gll16(&Bw[(size_t)(n0 + (q >> 3)) * DM + (t) * 64 + srcswz],           \
            &Bs[(b) * BN * 64 + q * 8]);                                     \
    }                                                                        \
  } while (0)

  STAGE2(0, 0);
  __syncthreads();
  int buf = 0;
  const int arow0 = wr * (BM / MW) + (lane & 15);
  const int brow0 = wc * (BN / NW) + (lane & 15);
  const int c0 = (((lane >> 4)) ^ (lane & 7)) * 8;      // kk=0 chunk (XOR row&7 = lane&7)
  const int c1 = ((4 + (lane >> 4)) ^ (lane & 7)) * 8;  // kk=1 chunk
  for (int t = 0; t < NT; ++t) {
    if (t + 1 < NT) STAGE2(t + 1, buf ^ 1);
    short8 af[MI][2], bf[NJ][2];
#pragma unroll
    for (int i = 0; i < MI; ++i) {
      const int r = buf * BM * 64 + (arow0 + i * 16) * 64;
      af[i][0] = *(const short8*)&As[r + c0];
      af[i][1] = *(const short8*)&As[r + c1];
    }
#pragma unroll
    for (int j = 0; j < NJ; ++j) {
      const int r = buf * BN * 64 + (brow0 + j * 16) * 64;
      bf[j][0] = *(const short8*)&Bs[r + c0];
      bf[j][1] = *(const short8*)&Bs[r + c1];
    }
#pragma unroll
    for (int i = 0; i < MI; ++i)
#pragma unroll
      for (int j = 0; j < NJ; ++j) {
        acc[i][j] = __builtin_amdgcn_mfma_f32_16x16x32_bf16(af[i][0], bf[j][0], acc[i][j], 0, 0, 0);
        acc[i][j] = __builtin_amdgcn_mfma_f32_16x16x32_bf16(af[i][1], bf[j][1], acc[i][j], 0, 0, 0);
      }
    __syncthreads();
    buf ^= 1;
  }
#undef STAGE2
}

// ---------------- fused QKV projection + bias + RoPE + layout ----------------
// Tile 256x192, 512 threads = 8 waves (4m x 2n), grid 256 1-D n-major.
__global__ __launch_bounds__(512, 2) void qkv_kernel(
    const u16* __restrict__ xb, const u16* __restrict__ wqkv,
    const float* __restrict__ bq, const float* __restrict__ bk, const float* __restrict__ bv,
    const float* __restrict__ ctab, const float* __restrict__ stab,
    u16* __restrict__ qbuf, u16* __restrict__ kbuf, u16* __restrict__ vt) {
  __shared__ __align__(16) u16 As[2 * 256 * 64];   // 64 KB
  __shared__ __align__(16) u16 Bs[2 * 192 * 64];   // 48 KB
  const int lin = blockIdx.x;                      // 256 = 16 n-groups * 16 m
  const int m0 = (lin & 15) * 256;
  const int n0 = (lin >> 4) * 192;                 // fused col across Wq|Wk|Wv
  f32x4 acc[4][6];
#pragma unroll
  for (int i = 0; i < 4; ++i)
#pragma unroll
    for (int j = 0; j < 6; ++j)
#pragma unroll
      for (int r = 0; r < 4; ++r) acc[i][j][r] = 0.f;
  gemm_pipe2<256, 192, 4, 3, 4, 6, 4, 2>(xb, wqkv, m0, n0, As, Bs, acc);

  const int lane = threadIdx.x & 63, wave = threadIdx.x >> 6;
  const int wr = wave >> 1, wc = wave & 1;
#pragma unroll
  for (int i = 0; i < 4; ++i) {
#pragma unroll
    for (int j = 0; j < 6; ++j) {
      const int e = n0 + wc * 96 + j * 16 + (lane & 15);   // global fused col
      const int mode = e >> 10;                             // 0=q 1=k 2=v (uniform per j-block)
      const float* bias = mode == 0 ? bq : (mode == 1 ? bk : bv);
      const float bval = bias[e & 1023];
      const int h = (e >> 6) & 15, hd = e & 63;
#pragma unroll
      for (int r = 0; r < 4; ++r) {
        const int m = m0 + wr * 64 + i * 16 + ((lane >> 4) * 4) + r;
        const int b = m >> 10, t = m & 1023;
        float v = acc[i][j][r] + bval;
        if (mode < 2) {
          float p = __shfl_xor(v, 1);  // partner within the (even,odd) pair
          const int fi = hd >> 1;
          const float cc = ctab[t * 32 + fi], ss = stab[t * 32 + fi];
          v = (hd & 1) ? (v * cc + p * ss) : (v * cc - p * ss);
          u16* dst = mode == 0 ? qbuf : kbuf;
          dst[(((size_t)(b * NH + h) * T_SEQ + t) << 6) + hd] = f2bf(v);
        } else {
          vt[(((size_t)(b * NH + h) * HDIM + hd) << 10) + t] = f2bf(v);
        }
      }
    }
  }
}

// ---------------- flash attention (R9 paired, proven) ----------------
// Block = (b,h) x {q-tile qt, 15-qt}: uniform 17 KV tiles. 4 waves x 16 rows.
__global__ __launch_bounds__(256) void attn_kernel(
    const u16* __restrict__ qbuf, const u16* __restrict__ kbuf,
    const u16* __restrict__ vtb, u16* __restrict__ ctx) {
  __shared__ __align__(16) u16 Ks[2][64 * 64];   // [kv][hd] swizzled
  __shared__ __align__(16) u16 Vs[2][64 * 64];   // [hd][kv] swizzled (V^T tile)
  __shared__ __align__(16) u16 Psm[4][16 * 64];  // per-wave P, swizzled
  const int bh = blockIdx.x;
  const int b = bh >> 4, h = bh & 15;
  const int tid = threadIdx.x, lane = tid & 63, wave = tid >> 6;
  const u16* Qp = qbuf + (size_t)bh * T_SEQ * HDIM;
  const u16* Kp = kbuf + (size_t)bh * T_SEQ * HDIM;
  const u16* Vp = vtb + (size_t)bh * HDIM * T_SEQ;
  u16* Pw = &Psm[wave][0];
  const float SC = 0.18033688f;                  // 0.125 * log2(e)

  const int srow = tid >> 3;                     // staging row (0..31, +32 for c=1)
  const int schx = ((tid & 7) ^ (srow & 7)) * 8; // pre-swizzled chunk (u16 offset)
  const int lx = lane & 7;                       // row&7 for all read rows below

  short8 onesf;
#pragma unroll
  for (int i = 0; i < 8; ++i) onesf[i] = (short)0x3F80;  // bf16 1.0

#define STG(kvt, bb)                                                            \
  do {                                                                          \
    _Pragma("unroll") for (int c = 0; c < 2; ++c) {                             \
      const int rr = c * 32 + srow;                                             \
      gll16(&Kp[(kvt) * 4096 + rr * 64 + schx], &Ks[bb][c * 2048 + tid * 8]);   \
      gll16(&Vp[(size_t)rr * T_SEQ + (kvt) * 64 + schx], &Vs[bb][c * 2048 + tid * 8]); \
    }                                                                           \
  } while (0)

  for (int phase = 0; phase < 2; ++phase) {
    const int qt = phase ? (15 - (int)blockIdx.y) : (int)blockIdx.y;
    const int q0 = qt * 64;
    const int nkv = qt + 1;
    const int qrow = q0 + wave * 16 + (lane & 15);
    const short8 qf0 = *(const short8*)&Qp[qrow * 64 + ((lane >> 4) * 8)];
    const short8 qf1 = *(const short8*)&Qp[qrow * 64 + 32 + ((lane >> 4) * 8)];

    f32x4 acc_o[4], accl;
    float m_r[4];
#pragma unroll
    for (int i = 0; i < 4; ++i) {
#pragma unroll
      for (int r = 0; r < 4; ++r) acc_o[i][r] = 0.f;
      accl[i] = 0.f;
      m_r[i] = -__builtin_inff();
    }

    __syncthreads();   // previous phase's readers done before restaging buf0
    STG(0, 0);
    int cur = 0;

    for (int kvt = 0; kvt < nkv; ++kvt) {
      __syncthreads();                       // buf[cur] staged (vmcnt drained)
      if (kvt + 1 < nkv) STG(kvt + 1, cur ^ 1);

      // S = Q K^T (16x64 per wave), scaled into exp2 domain
      f32x4 sacc[4];
#pragma unroll
      for (int cb = 0; cb < 4; ++cb) {
#pragma unroll
        for (int r = 0; r < 4; ++r) sacc[cb][r] = 0.f;
        const int krow = cb * 16 + (lane & 15);
        const short8 kf0 = *(const short8*)&Ks[cur][krow * 64 + (((lane >> 4) ^ lx) * 8)];
        const short8 kf1 = *(const short8*)&Ks[cur][krow * 64 + (((4 + (lane >> 4)) ^ lx) * 8)];
        sacc[cb] = __builtin_amdgcn_mfma_f32_16x16x32_bf16(qf0, kf0, sacc[cb], 0, 0, 0);
        sacc[cb] = __builtin_amdgcn_mfma_f32_16x16x32_bf16(qf1, kf1, sacc[cb], 0, 0, 0);
      }
      if (kvt == qt) {
        // diagonal tile: scale + causal mask
        const int trow_base = q0 + wave * 16 + ((lane >> 4) * 4);
#pragma unroll
        for (int cb = 0; cb < 4; ++cb) {
          const int scol = kvt * 64 + cb * 16 + (lane & 15);
#pragma unroll
          for (int r = 0; r < 4; ++r)
            sacc[cb][r] = (scol > trow_base + r) ? -__builtin_inff() : sacc[cb][r] * SC;
        }
      } else {
#pragma unroll
        for (int cb = 0; cb < 4; ++cb)
#pragma unroll
          for (int r = 0; r < 4; ++r) sacc[cb][r] *= SC;
      }
      // online softmax: row-max via 4-round shuffle; row-sum via MFMA below
      float mt[4];
#pragma unroll
      for (int r = 0; r < 4; ++r)
        mt[r] = fmaxf(fmaxf(sacc[0][r], sacc[1][r]), fmaxf(sacc[2][r], sacc[3][r]));
#pragma unroll
      for (int off = 1; off < 16; off <<= 1)
#pragma unroll
        for (int r = 0; r < 4; ++r) mt[r] = fmaxf(mt[r], __shfl_xor(mt[r], off));
      float sf[4];
#pragma unroll
      for (int r = 0; r < 4; ++r) {
        const float mn = fmaxf(m_r[r], mt[r]);
        sf[r] = exp2f(m_r[r] - mn);
        m_r[r] = mn;
      }
#pragma unroll
      for (int cb = 0; cb < 4; ++cb)
#pragma unroll
        for (int r = 0; r < 4; ++r) sacc[cb][r] = exp2f(sacc[cb][r] - m_r[r]);
#pragma unroll
      for (int r = 0; r < 4; ++r) accl[r] *= sf[r];
#pragma unroll
      for (int hb = 0; hb < 4; ++hb)
#pragma unroll
        for (int r = 0; r < 4; ++r) acc_o[hb][r] *= sf[r];

      // P (C-layout) -> LDS (swizzled) -> A-layout
#pragma unroll
      for (int cb = 0; cb < 4; ++cb)
#pragma unroll
        for (int r = 0; r < 4; ++r) {
          const int prow = (lane >> 4) * 4 + r;
          Pw[prow * 64 + ((cb * 16 + (lane & 15)) ^ ((prow & 7) << 3))] = f2bf(sacc[cb][r]);
        }

      // O += P V; l += P * ones
      const int prr = lane & 15;
#pragma unroll
      for (int kc = 0; kc < 2; ++kc) {
        const short8 pf = *(const short8*)&Pw[prr * 64 + (((kc * 4 + (lane >> 4)) ^ lx) * 8)];
        accl = __builtin_amdgcn_mfma_f32_16x16x32_bf16(pf, onesf, accl, 0, 0, 0);
#pragma unroll
        for (int hb = 0; hb < 4; ++hb) {
          const int vrow = hb * 16 + (lane & 15);
          const short8 vf = *(const short8*)&Vs[cur][vrow * 64 + (((kc * 4 + (lane >> 4)) ^ lx) * 8)];
          acc_o[hb] = __builtin_amdgcn_mfma_f32_16x16x32_bf16(pf, vf, acc_o[hb], 0, 0, 0);
        }
      }
      cur ^= 1;
    }

    // epilogue: ctx[b][t][h][hd] bf16
#pragma unroll
    for (int hb = 0; hb < 4; ++hb) {
      const int hd = hb * 16 + (lane & 15);
#pragma unroll
      for (int r = 0; r < 4; ++r) {
        const int t = q0 + wave * 16 + ((lane >> 4) * 4) + r;
        const float v = acc_o[hb][r] / accl[r];
        ctx[((size_t)(b * T_SEQ + t) * NH + h) * HDIM + hd] = f2bf(v);
      }
    }
  }
#undef STG
}

// ---------------- output projection -> fp32 d_out (R9) ----------------
// Tile 64x128, grid 512 1-D, n-major: n0 = lin/64, m0 = lin%64.
__global__ __launch_bounds__(256, 2) void oproj_kernel(
    const u16* __restrict__ ctx, const u16* __restrict__ Wob,
    const float* __restrict__ bo, float* __restrict__ out) {
  __shared__ __align__(16) u16 As[2 * 64 * 64];    // 16 KB
  __shared__ __align__(16) u16 Bs[2 * 128 * 64];   // 32 KB
  const int lin = blockIdx.x;                      // 512 = 8 n-groups * 64 m
  const int m0 = (lin & 63) * 64;
  const int n0 = (lin >> 6) * 128;
  f32x4 acc[2][4];
#pragma unroll
  for (int i = 0; i < 2; ++i)
#pragma unroll
    for (int j = 0; j < 4; ++j)
#pragma unroll
      for (int r = 0; r < 4; ++r) acc[i][j][r] = 0.f;
  gemm_pipe2<64, 128, 2, 4, 2, 4, 2, 2>(ctx, Wob, m0, n0, As, Bs, acc);
  const int lane = threadIdx.x & 63, wave = threadIdx.x >> 6;
  const int wr = wave >> 1, wc = wave & 1;
#pragma unroll
  for (int i = 0; i < 2; ++i)
#pragma unroll
    for (int j = 0; j < 4; ++j) {
      const int e = n0 + wc * 64 + j * 16 + (lane & 15);
      const float bval = bo[e];
#pragma unroll
      for (int r = 0; r < 4; ++r) {
        const int m = m0 + wr * 32 + i * 16 + ((lane >> 4) * 4) + r;
        out[(size_t)m * DM + e] = acc[i][j][r] + bval;
      }
    }
}

extern "C" void kernel_launch(void* const* d_in, const int* in_sizes, int n_in,
                              void* d_out, int out_size, void* d_ws, size_t ws_size,
                              hipStream_t stream) {
  const float* x  = (const float*)d_in[0];
  const float* Wq = (const float*)d_in[1];
  const float* bq = (const float*)d_in[2];
  const float* Wk = (const float*)d_in[3];
  const float* bk = (const float*)d_in[4];
  const float* Wv = (const float*)d_in[5];
  const float* bv = (const float*)d_in[6];
  const float* Wo = (const float*)d_in[7];
  const float* bo = (const float*)d_in[8];

  char* w = (char*)d_ws;
  u16* xb   = (u16*)(w);
  u16* wall = (u16*)(w + (8ull << 20));   // Wq|Wk|Wv|Wo bf16, 2MB each
  u16* wob  = (u16*)(w + (14ull << 20));
  u16* qb   = (u16*)(w + (16ull << 20));
  u16* kb   = (u16*)(w + (24ull << 20));
  u16* vtb  = (u16*)(w + (32ull << 20));
  u16* ctxb = (u16*)(w + (40ull << 20));
  float* ctab = (float*)(w + (48ull << 20));
  float* stab = ctab + T_SEQ * 32;

  prep_kernel<<<dim3(8192 + 128), 256, 0, stream>>>(x, Wq, Wk, Wv, Wo, xb, wall, ctab, stab);
  qkv_kernel<<<dim3(256), 512, 0, stream>>>(
      xb, wall, bq, bk, bv, ctab, stab, qb, kb, vtb);
  attn_kernel<<<dim3(64, 8), 256, 0, stream>>>(qb, kb, vtb, ctxb);
  oproj_kernel<<<dim3(512), 256, 0, stream>>>(ctxb, wob, bo, (float*)d_out);
}

// Round 12
// 105.799 us; speedup vs baseline: 1.0746x; 1.0441x over previous
//
#include <hip/hip_runtime.h>

// MHA: B=4, T=1024, D=1024, H=16, HD=64. Causal mask, interleaved RoPE.
// bf16 MFMA (16x16x32) everywhere, fp32 accumulate.
// R12: attn KVBLK=128 (half the barrier drains; 80KB dynamic LDS, 2/CU;
// uniform pairing qt/15-qt = 9 tiles/block). qkv reverted to R4-exact
// (128x192, 2-D grid, 48.9us best). oproj = R9.

#define T_SEQ 1024
#define NH    16
#define HDIM  64
#define DM    1024
#define MTOK  4096   // B*T

typedef __attribute__((ext_vector_type(8))) short short8;
typedef __attribute__((ext_vector_type(4))) float f32x4;
typedef unsigned short u16;

__device__ __forceinline__ u16 f2bf(float f) {
  unsigned int u = __builtin_bit_cast(unsigned int, f);
  u += 0x7fffu + ((u >> 16) & 1u);
  return (u16)(u >> 16);
}

// async global->LDS, 16B per lane. LDS dest must be wave-uniform base + lane*16.
__device__ __forceinline__ void gll16(const void* g, void* l) {
  __builtin_amdgcn_global_load_lds(
      (const __attribute__((address_space(1))) unsigned int*)(unsigned long long)(g),
      (__attribute__((address_space(3))) unsigned int*)(unsigned int)(unsigned long long)(l),
      16, 0, 0);
}

// ---------------- prep: x->bf16, W->bf16 (fused qkv+o), rope tables ----------------
__global__ void prep_kernel(const float* __restrict__ x,
                            const float* __restrict__ Wq, const float* __restrict__ Wk,
                            const float* __restrict__ Wv, const float* __restrict__ Wo,
                            u16* __restrict__ xb, u16* __restrict__ wall,
                            float* __restrict__ ctab, float* __restrict__ stab) {
  const int bid = blockIdx.x, tid = threadIdx.x;
  if (bid < 8192) {
    const float* src;
    u16* dst;
    int i;
    if (bid < 4096) {
      src = x; dst = xb; i = bid * 256 + tid;
    } else {
      const int w = (bid - 4096) >> 10;
      src = w == 0 ? Wq : w == 1 ? Wk : w == 2 ? Wv : Wo;
      dst = wall + (size_t)w * (DM * DM);
      i = ((bid - 4096) & 1023) * 256 + tid;
    }
    float4 f = ((const float4*)src)[i];
    unsigned long long pk = (unsigned long long)f2bf(f.x)
                          | ((unsigned long long)f2bf(f.y) << 16)
                          | ((unsigned long long)f2bf(f.z) << 32)
                          | ((unsigned long long)f2bf(f.w) << 48);
    ((unsigned long long*)dst)[i] = pk;
  } else {
    const int idx = (bid - 8192) * 256 + tid;  // T*32
    const int t = idx >> 5, i = idx & 31;
    float inv = powf(10000.f, -(float)i * (1.0f / 32.0f));
    float f = (float)t * inv;
    ctab[idx] = cosf(f);
    stab[idx] = sinf(f);
  }
}

// ---------------- single-barrier pipelined GEMM mainloop (R4, proven) ----------------
template<int BM, int BN, int AI, int BI, int MI, int NJ>
__device__ __forceinline__ void gemm_pipe2(
    const u16* __restrict__ A, const u16* __restrict__ Bw,
    int m0, int n0, u16* As, u16* Bs, f32x4 acc[MI][NJ]) {
  const int tid = threadIdx.x, lane = tid & 63, wave = tid >> 6;
  const int wr = wave >> 1, wc = wave & 1;
  const int srcswz = ((lane & 7) ^ (lane >> 3)) * 8;  // u16 offset within K-slice
  const int NT = DM / 64;

#define STAGE2(t, b)                                                         \
  do {                                                                       \
    _Pragma("unroll") for (int i = 0; i < AI; ++i) {                         \
      const int q = (wave * AI + i) * 64 + lane;                             \
      gll16(&A[(size_t)(m0 + (q >> 3)) * DM + (t) * 64 + srcswz],            \
            &As[(b) * BM * 64 + q * 8]);                                     \
    }                                                                        \
    _Pragma("unroll") for (int i = 0; i < BI; ++i) {                         \
      const int q = (wave * BI + i) * 64 + lane;                             \
      gll16(&Bw[(size_t)(n0 + (q >> 3)) * DM + (t) * 64 + srcswz],           \
            &Bs[(b) * BN * 64 + q * 8]);                                     \
    }                                                                        \
  } while (0)

  STAGE2(0, 0);
  __syncthreads();
  int buf = 0;
  const int arow0 = wr * (BM / 2) + (lane & 15);
  const int brow0 = wc * (BN / 2) + (lane & 15);
  const int c0 = (((lane >> 4)) ^ (lane & 7)) * 8;      // kk=0 chunk (XOR row&7 = lane&7)
  const int c1 = ((4 + (lane >> 4)) ^ (lane & 7)) * 8;  // kk=1 chunk
  for (int t = 0; t < NT; ++t) {
    if (t + 1 < NT) STAGE2(t + 1, buf ^ 1);
    short8 af[MI][2], bf[NJ][2];
#pragma unroll
    for (int i = 0; i < MI; ++i) {
      const int r = buf * BM * 64 + (arow0 + i * 16) * 64;
      af[i][0] = *(const short8*)&As[r + c0];
      af[i][1] = *(const short8*)&As[r + c1];
    }
#pragma unroll
    for (int j = 0; j < NJ; ++j) {
      const int r = buf * BN * 64 + (brow0 + j * 16) * 64;
      bf[j][0] = *(const short8*)&Bs[r + c0];
      bf[j][1] = *(const short8*)&Bs[r + c1];
    }
#pragma unroll
    for (int i = 0; i < MI; ++i)
#pragma unroll
      for (int j = 0; j < NJ; ++j) {
        acc[i][j] = __builtin_amdgcn_mfma_f32_16x16x32_bf16(af[i][0], bf[j][0], acc[i][j], 0, 0, 0);
        acc[i][j] = __builtin_amdgcn_mfma_f32_16x16x32_bf16(af[i][1], bf[j][1], acc[i][j], 0, 0, 0);
      }
    __syncthreads();
    buf ^= 1;
  }
#undef STAGE2
}

// ---------------- fused QKV projection + bias + RoPE + layout (R4-exact) ----------------
// Tile 128x192, grid (16 n, 32 m) 2-D = 512 blocks = 2/CU.
__global__ __launch_bounds__(256, 2) void qkv_kernel(
    const u16* __restrict__ xb, const u16* __restrict__ wqkv,
    const float* __restrict__ bq, const float* __restrict__ bk, const float* __restrict__ bv,
    const float* __restrict__ ctab, const float* __restrict__ stab,
    u16* __restrict__ qbuf, u16* __restrict__ kbuf, u16* __restrict__ vt) {
  __shared__ __align__(16) u16 As[2 * 128 * 64];   // 32 KB
  __shared__ __align__(16) u16 Bs[2 * 192 * 64];   // 48 KB
  const int m0 = blockIdx.y * 128;
  const int n0 = blockIdx.x * 192;      // fused col across Wq|Wk|Wv
  f32x4 acc[4][6];
#pragma unroll
  for (int i = 0; i < 4; ++i)
#pragma unroll
    for (int j = 0; j < 6; ++j)
#pragma unroll
      for (int r = 0; r < 4; ++r) acc[i][j][r] = 0.f;
  gemm_pipe2<128, 192, 4, 6, 4, 6>(xb, wqkv, m0, n0, As, Bs, acc);

  const int lane = threadIdx.x & 63, wave = threadIdx.x >> 6;
  const int wr = wave >> 1, wc = wave & 1;
#pragma unroll
  for (int i = 0; i < 4; ++i) {
#pragma unroll
    for (int j = 0; j < 6; ++j) {
      const int e = n0 + wc * 96 + j * 16 + (lane & 15);   // global fused col
      const int mode = e >> 10;                             // 0=q 1=k 2=v (uniform per j-block)
      const float* bias = mode == 0 ? bq : (mode == 1 ? bk : bv);
      const float bval = bias[e & 1023];
      const int h = (e >> 6) & 15, hd = e & 63;
#pragma unroll
      for (int r = 0; r < 4; ++r) {
        const int m = m0 + wr * 64 + i * 16 + ((lane >> 4) * 4) + r;
        const int b = m >> 10, t = m & 1023;
        float v = acc[i][j][r] + bval;
        if (mode < 2) {
          float p = __shfl_xor(v, 1);  // partner within the (even,odd) pair
          const int fi = hd >> 1;
          const float cc = ctab[t * 32 + fi], ss = stab[t * 32 + fi];
          v = (hd & 1) ? (v * cc + p * ss) : (v * cc - p * ss);
          u16* dst = mode == 0 ? qbuf : kbuf;
          dst[(((size_t)(b * NH + h) * T_SEQ + t) << 6) + hd] = f2bf(v);
        } else {
          vt[(((size_t)(b * NH + h) * HDIM + hd) << 10) + t] = f2bf(v);
        }
      }
    }
  }
}

// ---------------- flash attention, KVBLK=128 ----------------
// Block = (b,h) x {q-tile qt, 15-qt}: uniform 9 x 128-wide KV tiles/block.
// 4 waves x 16 q-rows. LDS 80KB dynamic (K dbuf 32K, V^T dbuf 32K, P 16K)
// -> 2 blocks/CU. Swizzles: K rows [128][64] chunk^=(row&7); V^T/P rows
// [x][128] = two 64-col halves, within-half chunk^=(row&7).
__global__ __launch_bounds__(256) void attn_kernel(
    const u16* __restrict__ qbuf, const u16* __restrict__ kbuf,
    const u16* __restrict__ vtb, u16* __restrict__ ctx) {
  extern __shared__ __align__(16) u16 asmem[];
  u16* Ksm = asmem;            // 2 x 8192 u16 (128 kv x 64 hd each)
  u16* Vsm = asmem + 16384;    // 2 x 8192 u16 (64 hd x 128 kv each)
  u16* Pall = asmem + 32768;   // 4 waves x 2048 u16 (16 x 128)
  const int bh = blockIdx.x;
  const int b = bh >> 4, h = bh & 15;
  const int tid = threadIdx.x, lane = tid & 63, wave = tid >> 6;
  const u16* Qp = qbuf + (size_t)bh * T_SEQ * HDIM;
  const u16* Kp = kbuf + (size_t)bh * T_SEQ * HDIM;
  const u16* Vp = vtb + (size_t)bh * HDIM * T_SEQ;
  u16* Pw = Pall + wave * 2048;
  const float SC = 0.18033688f;                  // 0.125 * log2(e)
  const int lx = lane & 7;
  const int q4 = lane >> 4;                      // 0..3

  short8 onesf;
#pragma unroll
  for (int i = 0; i < 8; ++i) onesf[i] = (short)0x3F80;  // bf16 1.0

  // staging maps (4 rounds K + 4 rounds V per tile)
#define STG(kvt, bb)                                                             \
  do {                                                                           \
    _Pragma("unroll") for (int l = 0; l < 4; ++l) {                              \
      const int idx = l * 256 + tid;                                             \
      const int krow = idx >> 3, kch = (idx & 7) ^ (krow & 7);                   \
      gll16(&Kp[((kvt) * 128 + krow) * 64 + kch * 8], &Ksm[(bb) * 8192 + idx * 8]); \
    }                                                                            \
    _Pragma("unroll") for (int l = 0; l < 4; ++l) {                              \
      const int idx = l * 256 + tid;                                             \
      const int vrow = idx >> 4, c16 = idx & 15;                                 \
      const int sc = (c16 & 8) | ((c16 & 7) ^ (vrow & 7));                       \
      gll16(&Vp[(size_t)vrow * T_SEQ + (kvt) * 128 + sc * 8],                    \
            &Vsm[(bb) * 8192 + idx * 8]);                                        \
    }                                                                            \
  } while (0)

  for (int phase = 0; phase < 2; ++phase) {
    const int qt = phase ? (15 - (int)blockIdx.y) : (int)blockIdx.y;
    const int q0 = qt * 64;
    const int dkv = qt >> 1;           // diagonal 128-wide kv tile
    const int nkv = dkv + 1;
    const int qrow = q0 + wave * 16 + (lane & 15);
    const short8 qf0 = *(const short8*)&Qp[qrow * 64 + (q4 * 8)];
    const short8 qf1 = *(const short8*)&Qp[qrow * 64 + 32 + (q4 * 8)];

    f32x4 acc_o[4], accl;
    float m_r[4];
#pragma unroll
    for (int i = 0; i < 4; ++i) {
#pragma unroll
      for (int r = 0; r < 4; ++r) acc_o[i][r] = 0.f;
      accl[i] = 0.f;
      m_r[i] = -__builtin_inff();
    }

    __syncthreads();   // previous phase's readers done before restaging buf0
    STG(0, 0);
    int cur = 0;

    for (int kvt = 0; kvt < nkv; ++kvt) {
      __syncthreads();                       // buf[cur] staged (vmcnt drained)
      if (kvt + 1 < nkv) STG(kvt + 1, cur ^ 1);

      const u16* Kb = Ksm + cur * 8192;
      const u16* Vb = Vsm + cur * 8192;

      // S = Q K^T (16x128 per wave), scaled into exp2 domain
      f32x4 sacc[8];
#pragma unroll
      for (int cb = 0; cb < 8; ++cb) {
#pragma unroll
        for (int r = 0; r < 4; ++r) sacc[cb][r] = 0.f;
        const int krow = cb * 16 + (lane & 15);
        const short8 kf0 = *(const short8*)&Kb[krow * 64 + ((q4 ^ (krow & 7)) * 8)];
        const short8 kf1 = *(const short8*)&Kb[krow * 64 + (((4 + q4) ^ (krow & 7)) * 8)];
        sacc[cb] = __builtin_amdgcn_mfma_f32_16x16x32_bf16(qf0, kf0, sacc[cb], 0, 0, 0);
        sacc[cb] = __builtin_amdgcn_mfma_f32_16x16x32_bf16(qf1, kf1, sacc[cb], 0, 0, 0);
      }
      if (kvt == dkv) {
        // diagonal tile: scale + causal mask
        const int trow_base = q0 + wave * 16 + q4 * 4;
#pragma unroll
        for (int cb = 0; cb < 8; ++cb) {
          const int scol = kvt * 128 + cb * 16 + (lane & 15);
#pragma unroll
          for (int r = 0; r < 4; ++r)
            sacc[cb][r] = (scol > trow_base + r) ? -__builtin_inff() : sacc[cb][r] * SC;
        }
      } else {
#pragma unroll
        for (int cb = 0; cb < 8; ++cb)
#pragma unroll
          for (int r = 0; r < 4; ++r) sacc[cb][r] *= SC;
      }
      // online softmax: row-max via 4-round shuffle; row-sum via MFMA below
      float mt[4];
#pragma unroll
      for (int r = 0; r < 4; ++r) {
        mt[r] = fmaxf(fmaxf(sacc[0][r], sacc[1][r]), fmaxf(sacc[2][r], sacc[3][r]));
        mt[r] = fmaxf(mt[r], fmaxf(fmaxf(sacc[4][r], sacc[5][r]), fmaxf(sacc[6][r], sacc[7][r])));
      }
#pragma unroll
      for (int off = 1; off < 16; off <<= 1)
#pragma unroll
        for (int r = 0; r < 4; ++r) mt[r] = fmaxf(mt[r], __shfl_xor(mt[r], off));
      float sf[4];
#pragma unroll
      for (int r = 0; r < 4; ++r) {
        const float mn = fmaxf(m_r[r], mt[r]);
        sf[r] = exp2f(m_r[r] - mn);
        m_r[r] = mn;
      }
#pragma unroll
      for (int cb = 0; cb < 8; ++cb)
#pragma unroll
        for (int r = 0; r < 4; ++r) sacc[cb][r] = exp2f(sacc[cb][r] - m_r[r]);
#pragma unroll
      for (int r = 0; r < 4; ++r) accl[r] *= sf[r];
#pragma unroll
      for (int hb = 0; hb < 4; ++hb)
#pragma unroll
        for (int r = 0; r < 4; ++r) acc_o[hb][r] *= sf[r];

      // P (C-layout) -> LDS (two swizzled 64-col halves) -> A-layout
#pragma unroll
      for (int cb = 0; cb < 8; ++cb)
#pragma unroll
        for (int r = 0; r < 4; ++r) {
          const int prow = q4 * 4 + r;
          const int col = cb * 16 + (lane & 15);
          Pw[prow * 128 + (col & 64) + ((col & 63) ^ ((prow & 7) << 3))] = f2bf(sacc[cb][r]);
        }

      // O += P V; l += P * ones   (K=128: kc = 0..3)
      const int prr = lane & 15;
#pragma unroll
      for (int kc = 0; kc < 4; ++kc) {
        const int lc = kc * 4 + q4;   // logical 16B chunk 0..15
        const int pc = (lc & 8) | ((lc & 7) ^ (prr & 7));
        const short8 pf = *(const short8*)&Pw[prr * 128 + pc * 8];
        accl = __builtin_amdgcn_mfma_f32_16x16x32_bf16(pf, onesf, accl, 0, 0, 0);
#pragma unroll
        for (int hb = 0; hb < 4; ++hb) {
          const int vrow = hb * 16 + (lane & 15);
          const int vc = (lc & 8) | ((lc & 7) ^ (vrow & 7));
          const short8 vf = *(const short8*)&Vb[vrow * 128 + vc * 8];
          acc_o[hb] = __builtin_amdgcn_mfma_f32_16x16x32_bf16(pf, vf, acc_o[hb], 0, 0, 0);
        }
      }
      cur ^= 1;
    }

    // epilogue: ctx[b][t][h][hd] bf16
#pragma unroll
    for (int hb = 0; hb < 4; ++hb) {
      const int hd = hb * 16 + (lane & 15);
#pragma unroll
      for (int r = 0; r < 4; ++r) {
        const int t = q0 + wave * 16 + q4 * 4 + r;
        const float v = acc_o[hb][r] / accl[r];
        ctx[((size_t)(b * T_SEQ + t) * NH + h) * HDIM + hd] = f2bf(v);
      }
    }
  }
#undef STG
}

// ---------------- output projection -> fp32 d_out (R9) ----------------
// Tile 64x128, grid 512 1-D, n-major: n0 = lin/64, m0 = lin%64.
__global__ __launch_bounds__(256, 2) void oproj_kernel(
    const u16* __restrict__ ctx, const u16* __restrict__ Wob,
    const float* __restrict__ bo, float* __restrict__ out) {
  __shared__ __align__(16) u16 As[2 * 64 * 64];    // 16 KB
  __shared__ __align__(16) u16 Bs[2 * 128 * 64];   // 32 KB
  const int lin = blockIdx.x;                      // 512 = 8 n-groups * 64 m
  const int m0 = (lin & 63) * 64;
  const int n0 = (lin >> 6) * 128;
  f32x4 acc[2][4];
#pragma unroll
  for (int i = 0; i < 2; ++i)
#pragma unroll
    for (int j = 0; j < 4; ++j)
#pragma unroll
      for (int r = 0; r < 4; ++r) acc[i][j][r] = 0.f;
  gemm_pipe2<64, 128, 2, 4, 2, 4>(ctx, Wob, m0, n0, As, Bs, acc);
  const int lane = threadIdx.x & 63, wave = threadIdx.x >> 6;
  const int wr = wave >> 1, wc = wave & 1;
#pragma unroll
  for (int i = 0; i < 2; ++i)
#pragma unroll
    for (int j = 0; j < 4; ++j) {
      const int e = n0 + wc * 64 + j * 16 + (lane & 15);
      const float bval = bo[e];
#pragma unroll
      for (int r = 0; r < 4; ++r) {
        const int m = m0 + wr * 32 + i * 16 + ((lane >> 4) * 4) + r;
        out[(size_t)m * DM + e] = acc[i][j][r] + bval;
      }
    }
}

extern "C" void kernel_launch(void* const* d_in, const int* in_sizes, int n_in,
                              void* d_out, int out_size, void* d_ws, size_t ws_size,
                              hipStream_t stream) {
  const float* x  = (const float*)d_in[0];
  const float* Wq = (const float*)d_in[1];
  const float* bq = (const float*)d_in[2];
  const float* Wk = (const float*)d_in[3];
  const float* bk = (const float*)d_in[4];
  const float* Wv = (const float*)d_in[5];
  const float* bv = (const float*)d_in[6];
  const float* Wo = (const float*)d_in[7];
  const float* bo = (const float*)d_in[8];

  char* w = (char*)d_ws;
  u16* xb   = (u16*)(w);
  u16* wall = (u16*)(w + (8ull << 20));   // Wq|Wk|Wv|Wo bf16, 2MB each
  u16* wob  = (u16*)(w + (14ull << 20));
  u16* qb   = (u16*)(w + (16ull << 20));
  u16* kb   = (u16*)(w + (24ull << 20));
  u16* vtb  = (u16*)(w + (32ull << 20));
  u16* ctxb = (u16*)(w + (40ull << 20));
  float* ctab = (float*)(w + (48ull << 20));
  float* stab = ctab + T_SEQ * 32;

  hipFuncSetAttribute(reinterpret_cast<const void*>(attn_kernel),
                      hipFuncAttributeMaxDynamicSharedMemorySize, 81920);

  prep_kernel<<<dim3(8192 + 128), 256, 0, stream>>>(x, Wq, Wk, Wv, Wo, xb, wall, ctab, stab);
  qkv_kernel<<<dim3(3 * DM / 192, MTOK / 128), 256, 0, stream>>>(
      xb, wall, bq, bk, bv, ctab, stab, qb, kb, vtb);
  attn_kernel<<<dim3(64, 8), 256, 81920, stream>>>(qb, kb, vtb, ctxb);
  oproj_kernel<<<dim3(512), 256, 0, stream>>>(ctxb, wob, bo, (float*)d_out);
}